// Round 1
// baseline (295.695 us; speedup 1.0000x reference)
//
#include <hip/hip_runtime.h>

#define NN 50000
#define NE 640000
#define FDIM 128
#define FOUT 40

typedef unsigned int uint;
typedef unsigned short ushort;
typedef __attribute__((ext_vector_type(8))) __bf16 bf16x8;
typedef __attribute__((ext_vector_type(4))) float f32x4;

union BF8 { bf16x8 v; uint4 u; ushort s[8]; };

__device__ __forceinline__ ushort f2bf(float f){
  uint b = __float_as_uint(f);
  b += 0x7fffu + ((b >> 16) & 1u);   // RNE; inputs never NaN/Inf here
  return (ushort)(b >> 16);
}
__device__ __forceinline__ float bflo(uint v){ return __uint_as_float(v << 16); }
__device__ __forceinline__ float bfhi(uint v){ return __uint_as_float(v & 0xffff0000u); }

// ---------- dtype detector: edges int64 (ref) vs int32 (harness doc) ----------
__global__ void k_detect(const unsigned long long* __restrict__ e64, int* __restrict__ flag){
  if(blockIdx.x == 0 && threadIdx.x == 0){
    int ok = 1;
    for(int i = 0; i < 64; ++i)
      if(e64[i] >= 4294967296ULL) ok = 0;
    *flag = ok;  // 1 => data really is int64
  }
}
__device__ __forceinline__ int get_edge(const void* ep, int is64, int idx){
  return is64 ? (int)(((const long long*)ep)[idx]) : ((const int*)ep)[idx];
}

// ---------- f32 -> bf16 convert ----------
__global__ void k_cvt(const float4* __restrict__ in, ushort4* __restrict__ out, int n4){
  int i = blockIdx.x * blockDim.x + threadIdx.x;
  if(i >= n4) return;
  float4 v = in[i];
  ushort4 o; o.x = f2bf(v.x); o.y = f2bf(v.y); o.z = f2bf(v.z); o.w = f2bf(v.w);
  out[i] = o;
}

// ---------- CSR build ----------
__global__ void k_count(const void* __restrict__ edges, const int* __restrict__ flag,
                        int* __restrict__ deg){
  int e = blockIdx.x * blockDim.x + threadIdx.x;
  if(e >= NE) return;
  int is64 = *flag;
  int d = get_edge(edges, is64, NE + e);
  atomicAdd(&deg[d], 1);
}

__global__ void k_scan1(const int* __restrict__ deg, int* __restrict__ rp, int* __restrict__ bsum){
  __shared__ int s[256];
  int t = threadIdx.x;
  int i = blockIdx.x * 256 + t;
  int v = (i < NN) ? deg[i] : 0;
  s[t] = v; __syncthreads();
  for(int off = 1; off < 256; off <<= 1){
    int a = (t >= off) ? s[t - off] : 0;
    __syncthreads();
    s[t] += a;
    __syncthreads();
  }
  if(i < NN) rp[i] = s[t] - v;           // exclusive within block
  if(t == 255) bsum[blockIdx.x] = s[255];
}

__global__ void k_scan2(int* __restrict__ bsum, int nb){
  __shared__ int s[256];
  int t = threadIdx.x;
  int v = (t < nb) ? bsum[t] : 0;
  s[t] = v; __syncthreads();
  for(int off = 1; off < 256; off <<= 1){
    int a = (t >= off) ? s[t - off] : 0;
    __syncthreads();
    s[t] += a;
    __syncthreads();
  }
  if(t < nb) bsum[t] = s[t] - v;         // exclusive block offsets
}

__global__ void k_scan3(int* __restrict__ rp, const int* __restrict__ bsum){
  int i = blockIdx.x * 256 + threadIdx.x;
  if(i < NN) rp[i] += bsum[blockIdx.x];
  if(i == 0) rp[NN] = NE;
}

__global__ void k_fill(const void* __restrict__ edges, const int* __restrict__ flag,
                       const int* __restrict__ rp, int* __restrict__ cur, int* __restrict__ col){
  int e = blockIdx.x * blockDim.x + threadIdx.x;
  if(e >= NE) return;
  int is64 = *flag;
  int d = get_edge(edges, is64, NE + e);
  int s = get_edge(edges, is64, e);
  int p = rp[d] + atomicAdd(&cur[d], 1);
  col[p] = s;
}

// ---------- mean aggregation: one wave per node ----------
__global__ void k_agg(const ushort* __restrict__ feat, const int* __restrict__ rp,
                      const int* __restrict__ col, ushort* __restrict__ mean){
  int node = (blockIdx.x * blockDim.x + threadIdx.x) >> 6;
  int l = threadIdx.x & 63;
  if(node >= NN) return;
  int beg = rp[node], end = rp[node + 1];
  float a0 = 0.f, a1 = 0.f;
  int j = beg;
  for(; j + 1 < end; j += 2){
    int s0 = col[j], s1 = col[j + 1];
    uint v0 = *(const uint*)(feat + (size_t)s0 * FDIM + l * 2);
    uint v1 = *(const uint*)(feat + (size_t)s1 * FDIM + l * 2);
    a0 += bflo(v0) + bflo(v1);
    a1 += bfhi(v0) + bfhi(v1);
  }
  if(j < end){
    int s0 = col[j];
    uint v0 = *(const uint*)(feat + (size_t)s0 * FDIM + l * 2);
    a0 += bflo(v0); a1 += bfhi(v0);
  }
  float inv = 1.0f / (float)max(end - beg, 1);
  uint o = (uint)f2bf(a0 * inv) | ((uint)f2bf(a1 * inv) << 16);
  *(uint*)(mean + (size_t)node * FDIM + l * 2) = o;
}

// ---------- fused linear: out = relu(A1@Wl^T + b + A2@Wr^T), 128 outputs ----------
// block = 256 (4 waves); wave g owns cols [32g,32g+32); blockIdx = worker, 5 strips of 16 rows
__launch_bounds__(256)
__global__ void k_lin128(const ushort* __restrict__ A1, const ushort* __restrict__ A2,
                         const float* __restrict__ Wl, const float* __restrict__ Wr,
                         const float* __restrict__ bias, ushort* __restrict__ out){
  int g = threadIdx.x >> 6;
  int l = threadIdx.x & 63;
  int worker = blockIdx.x;
  int r16 = l & 15, q = l >> 4;

  BF8 bl[2][4], br[2][4];
#pragma unroll
  for(int tt = 0; tt < 2; ++tt){
    int colw = 32 * g + 16 * tt + r16;
    const float* pl = Wl + colw * FDIM + q * 8;
    const float* pr = Wr + colw * FDIM + q * 8;
#pragma unroll
    for(int ks = 0; ks < 4; ++ks){
      float4 x0 = *(const float4*)(pl + 32 * ks);
      float4 x1 = *(const float4*)(pl + 32 * ks + 4);
      BF8 t;
      t.s[0]=f2bf(x0.x); t.s[1]=f2bf(x0.y); t.s[2]=f2bf(x0.z); t.s[3]=f2bf(x0.w);
      t.s[4]=f2bf(x1.x); t.s[5]=f2bf(x1.y); t.s[6]=f2bf(x1.z); t.s[7]=f2bf(x1.w);
      bl[tt][ks] = t;
      float4 y0 = *(const float4*)(pr + 32 * ks);
      float4 y1 = *(const float4*)(pr + 32 * ks + 4);
      BF8 u;
      u.s[0]=f2bf(y0.x); u.s[1]=f2bf(y0.y); u.s[2]=f2bf(y0.z); u.s[3]=f2bf(y0.w);
      u.s[4]=f2bf(y1.x); u.s[5]=f2bf(y1.y); u.s[6]=f2bf(y1.z); u.s[7]=f2bf(y1.w);
      br[tt][ks] = u;
    }
  }
  float bv0 = bias[32 * g + r16];
  float bv1 = bias[32 * g + 16 + r16];

  for(int s = 0; s < 5; ++s){
    int m0 = (worker * 5 + s) * 16;
    BF8 a1[4], a2[4];
    const ushort* p1 = A1 + (size_t)(m0 + r16) * FDIM + q * 8;
    const ushort* p2 = A2 + (size_t)(m0 + r16) * FDIM + q * 8;
#pragma unroll
    for(int ks = 0; ks < 4; ++ks){
      a1[ks].u = *(const uint4*)(p1 + 32 * ks);
      a2[ks].u = *(const uint4*)(p2 + 32 * ks);
    }
    f32x4 acc0 = {0.f,0.f,0.f,0.f}, acc1 = {0.f,0.f,0.f,0.f};
#pragma unroll
    for(int ks = 0; ks < 4; ++ks){
      acc0 = __builtin_amdgcn_mfma_f32_16x16x32_bf16(a1[ks].v, bl[0][ks].v, acc0, 0, 0, 0);
      acc0 = __builtin_amdgcn_mfma_f32_16x16x32_bf16(a2[ks].v, br[0][ks].v, acc0, 0, 0, 0);
      acc1 = __builtin_amdgcn_mfma_f32_16x16x32_bf16(a1[ks].v, bl[1][ks].v, acc1, 0, 0, 0);
      acc1 = __builtin_amdgcn_mfma_f32_16x16x32_bf16(a2[ks].v, br[1][ks].v, acc1, 0, 0, 0);
    }
#pragma unroll
    for(int r = 0; r < 4; ++r){
      int row = m0 + q * 4 + r;
      float v0 = fmaxf(acc0[r] + bv0, 0.f);
      float v1 = fmaxf(acc1[r] + bv1, 0.f);
      out[(size_t)row * FDIM + 32 * g + r16]      = f2bf(v0);
      out[(size_t)row * FDIM + 32 * g + 16 + r16] = f2bf(v1);
    }
  }
}

// ---------- layer-3 linear (40 outputs, no relu), f32 z output ----------
// block = 192 (3 waves); wave g owns cols [16g,16g+16) masked at 40
__launch_bounds__(192)
__global__ void k_lin40(const ushort* __restrict__ A1, const ushort* __restrict__ A2,
                        const float* __restrict__ Wl, const float* __restrict__ Wr,
                        const float* __restrict__ bias, float* __restrict__ z){
  int g = threadIdx.x >> 6;
  int l = threadIdx.x & 63;
  int worker = blockIdx.x;
  int r16 = l & 15, q = l >> 4;
  int colw = 16 * g + r16;
  bool vcol = colw < FOUT;

  BF8 bl[4], br[4];
#pragma unroll
  for(int ks = 0; ks < 4; ++ks){
    BF8 t, u;
    if(vcol){
      const float* pl = Wl + colw * FDIM + q * 8 + 32 * ks;
      const float* pr = Wr + colw * FDIM + q * 8 + 32 * ks;
      float4 x0 = ((const float4*)pl)[0], x1 = ((const float4*)pl)[1];
      t.s[0]=f2bf(x0.x); t.s[1]=f2bf(x0.y); t.s[2]=f2bf(x0.z); t.s[3]=f2bf(x0.w);
      t.s[4]=f2bf(x1.x); t.s[5]=f2bf(x1.y); t.s[6]=f2bf(x1.z); t.s[7]=f2bf(x1.w);
      float4 y0 = ((const float4*)pr)[0], y1 = ((const float4*)pr)[1];
      u.s[0]=f2bf(y0.x); u.s[1]=f2bf(y0.y); u.s[2]=f2bf(y0.z); u.s[3]=f2bf(y0.w);
      u.s[4]=f2bf(y1.x); u.s[5]=f2bf(y1.y); u.s[6]=f2bf(y1.z); u.s[7]=f2bf(y1.w);
    } else {
      t.u = make_uint4(0,0,0,0);
      u.u = make_uint4(0,0,0,0);
    }
    bl[ks] = t; br[ks] = u;
  }
  float bv = vcol ? bias[colw] : 0.f;

  for(int s = 0; s < 5; ++s){
    int m0 = (worker * 5 + s) * 16;
    BF8 a1[4], a2[4];
    const ushort* p1 = A1 + (size_t)(m0 + r16) * FDIM + q * 8;
    const ushort* p2 = A2 + (size_t)(m0 + r16) * FDIM + q * 8;
#pragma unroll
    for(int ks = 0; ks < 4; ++ks){
      a1[ks].u = *(const uint4*)(p1 + 32 * ks);
      a2[ks].u = *(const uint4*)(p2 + 32 * ks);
    }
    f32x4 acc = {0.f,0.f,0.f,0.f};
#pragma unroll
    for(int ks = 0; ks < 4; ++ks){
      acc = __builtin_amdgcn_mfma_f32_16x16x32_bf16(a1[ks].v, bl[ks].v, acc, 0, 0, 0);
      acc = __builtin_amdgcn_mfma_f32_16x16x32_bf16(a2[ks].v, br[ks].v, acc, 0, 0, 0);
    }
    if(vcol){
#pragma unroll
      for(int r = 0; r < 4; ++r){
        int row = m0 + q * 4 + r;
        z[(size_t)row * FOUT + colw] = acc[r] + bv;
      }
    }
  }
}

// ---------- log_softmax over 40 cols, thread per row ----------
__global__ void k_lsm(const float* __restrict__ z, float* __restrict__ out){
  int r = blockIdx.x * blockDim.x + threadIdx.x;
  if(r >= NN) return;
  const float* p = z + (size_t)r * FOUT;
  float m = p[0];
#pragma unroll
  for(int i = 1; i < FOUT; ++i) m = fmaxf(m, p[i]);
  float ssum = 0.f;
#pragma unroll
  for(int i = 0; i < FOUT; ++i) ssum += __expf(p[i] - m);
  float lse = m + __logf(ssum);
  float* o = out + (size_t)r * FOUT;
#pragma unroll
  for(int i = 0; i < FOUT; ++i) o[i] = p[i] - lse;
}

extern "C" void kernel_launch(void* const* d_in, const int* in_sizes, int n_in,
                              void* d_out, int out_size, void* d_ws, size_t ws_size,
                              hipStream_t stream){
  const float* x   = (const float*)d_in[0];
  const void*  edges = d_in[1];
  const float* W1l = (const float*)d_in[2];
  const float* b1  = (const float*)d_in[3];
  const float* W1r = (const float*)d_in[4];
  const float* W2l = (const float*)d_in[5];
  const float* b2  = (const float*)d_in[6];
  const float* W2r = (const float*)d_in[7];
  const float* W3l = (const float*)d_in[8];
  const float* b3  = (const float*)d_in[9];
  const float* W3r = (const float*)d_in[10];
  float* out = (float*)d_out;

  char* ws = (char*)d_ws;
  size_t off = 0;
  auto alloc = [&](size_t bytes)->void*{
    void* p = ws + off;
    off += (bytes + 255) & ~(size_t)255;
    return p;
  };
  ushort* xb   = (ushort*)alloc((size_t)NN * FDIM * 2);
  ushort* h1   = (ushort*)alloc((size_t)NN * FDIM * 2);
  ushort* h2   = (ushort*)alloc((size_t)NN * FDIM * 2);
  ushort* mean = (ushort*)alloc((size_t)NN * FDIM * 2);
  int*    deg  = (int*)alloc((size_t)NN * 4);        // reused as cursor
  int*    rp   = (int*)alloc((size_t)(NN + 1) * 4);
  int*    col  = (int*)alloc((size_t)NE * 4);
  int*    bsum = (int*)alloc(1024);
  int*    flag = (int*)alloc(256);
  float*  z    = (float*)xb;                          // xb dead after layer-1 linear

  hipMemsetAsync(deg, 0, (size_t)NN * 4, stream);
  k_detect<<<1, 64, 0, stream>>>((const unsigned long long*)edges, flag);
  k_cvt<<<(NN * FDIM / 4 + 255) / 256, 256, 0, stream>>>((const float4*)x, (ushort4*)xb, NN * FDIM / 4);
  k_count<<<(NE + 255) / 256, 256, 0, stream>>>(edges, flag, deg);
  int nb = (NN + 255) / 256;  // 196
  k_scan1<<<nb, 256, 0, stream>>>(deg, rp, bsum);
  k_scan2<<<1, 256, 0, stream>>>(bsum, nb);
  k_scan3<<<nb, 256, 0, stream>>>(rp, bsum);
  hipMemsetAsync(deg, 0, (size_t)NN * 4, stream);
  k_fill<<<(NE + 255) / 256, 256, 0, stream>>>(edges, flag, rp, deg, col);

  // layer 1
  k_agg<<<NN / 4, 256, 0, stream>>>(xb, rp, col, mean);
  k_lin128<<<625, 256, 0, stream>>>(mean, xb, W1l, W1r, b1, h1);
  // layer 2
  k_agg<<<NN / 4, 256, 0, stream>>>(h1, rp, col, mean);
  k_lin128<<<625, 256, 0, stream>>>(mean, h1, W2l, W2r, b2, h2);
  // layer 3
  k_agg<<<NN / 4, 256, 0, stream>>>(h2, rp, col, mean);
  k_lin40<<<625, 192, 0, stream>>>(mean, h2, W3l, W3r, b3, z);
  k_lsm<<<(NN + 255) / 256, 256, 0, stream>>>(z, out);
}

// Round 2
// 244.097 us; speedup vs baseline: 1.2114x; 1.2114x over previous
//
#include <hip/hip_runtime.h>

#define NN 50000
#define NE 640000
#define FDIM 128
#define FOUT 40

typedef unsigned int uint;
typedef unsigned short ushort;
typedef __attribute__((ext_vector_type(8))) __bf16 bf16x8;
typedef __attribute__((ext_vector_type(4))) float f32x4;

union BF8 { bf16x8 v; uint4 u; ushort s[8]; };

__device__ __forceinline__ ushort f2bf(float f){
  uint b = __float_as_uint(f);
  b += 0x7fffu + ((b >> 16) & 1u);   // RNE; inputs never NaN/Inf here
  return (ushort)(b >> 16);
}
__device__ __forceinline__ float bflo(uint v){ return __uint_as_float(v << 16); }
__device__ __forceinline__ float bfhi(uint v){ return __uint_as_float(v & 0xffff0000u); }

// ---------- dtype detector: edges int64 (ref) vs int32 (harness doc) ----------
__global__ void k_detect(const unsigned long long* __restrict__ e64, int* __restrict__ flag){
  if(blockIdx.x == 0 && threadIdx.x == 0){
    int ok = 1;
    for(int i = 0; i < 64; ++i)
      if(e64[i] >= 4294967296ULL) ok = 0;
    *flag = ok;  // 1 => data really is int64
  }
}
__device__ __forceinline__ int get_edge(const void* ep, int is64, int idx){
  return is64 ? (int)(((const long long*)ep)[idx]) : ((const int*)ep)[idx];
}

// ---------- f32 -> bf16 convert ----------
__global__ void k_cvt(const float4* __restrict__ in, ushort4* __restrict__ out, int n4){
  int i = blockIdx.x * blockDim.x + threadIdx.x;
  if(i >= n4) return;
  float4 v = in[i];
  ushort4 o; o.x = f2bf(v.x); o.y = f2bf(v.y); o.z = f2bf(v.z); o.w = f2bf(v.w);
  out[i] = o;
}

// ---------- CSR build ----------
__global__ void k_count(const void* __restrict__ edges, const int* __restrict__ flag,
                        int* __restrict__ deg){
  int e = blockIdx.x * blockDim.x + threadIdx.x;
  if(e >= NE) return;
  int is64 = *flag;
  int d = get_edge(edges, is64, NE + e);
  atomicAdd(&deg[d], 1);
}

__global__ void k_scan1(const int* __restrict__ deg, int* __restrict__ rp, int* __restrict__ bsum){
  __shared__ int s[256];
  int t = threadIdx.x;
  int i = blockIdx.x * 256 + t;
  int v = (i < NN) ? deg[i] : 0;
  s[t] = v; __syncthreads();
  for(int off = 1; off < 256; off <<= 1){
    int a = (t >= off) ? s[t - off] : 0;
    __syncthreads();
    s[t] += a;
    __syncthreads();
  }
  if(i < NN) rp[i] = s[t] - v;           // exclusive within block
  if(t == 255) bsum[blockIdx.x] = s[255];
}

__global__ void k_scan2(int* __restrict__ bsum, int nb){
  __shared__ int s[256];
  int t = threadIdx.x;
  int v = (t < nb) ? bsum[t] : 0;
  s[t] = v; __syncthreads();
  for(int off = 1; off < 256; off <<= 1){
    int a = (t >= off) ? s[t - off] : 0;
    __syncthreads();
    s[t] += a;
    __syncthreads();
  }
  if(t < nb) bsum[t] = s[t] - v;         // exclusive block offsets
}

__global__ void k_scan3(int* __restrict__ rp, const int* __restrict__ bsum){
  int i = blockIdx.x * 256 + threadIdx.x;
  if(i < NN) rp[i] += bsum[blockIdx.x];
  if(i == 0) rp[NN] = NE;
}

__global__ void k_fill(const void* __restrict__ edges, const int* __restrict__ flag,
                       const int* __restrict__ rp, int* __restrict__ cur, int* __restrict__ col){
  int e = blockIdx.x * blockDim.x + threadIdx.x;
  if(e >= NE) return;
  int is64 = *flag;
  int d = get_edge(edges, is64, NE + e);
  int s = get_edge(edges, is64, e);
  int p = rp[d] + atomicAdd(&cur[d], 1);
  col[p] = s;
}

// ---------- mean aggregation: one wave per node ----------
// lanes = 16 feature-chunks x 4 edge-slots: lane l reads the 16B chunk (l&15)
// of the row for edge j+(l>>4). Edge indices preloaded 64-wide and distributed
// via ds_bpermute -> all gathers in the degree loop are independent.
__global__ void k_agg(const ushort* __restrict__ feat, const int* __restrict__ rp,
                      const int* __restrict__ col, ushort* __restrict__ mean){
  int node = (blockIdx.x * blockDim.x + threadIdx.x) >> 6;
  if(node >= NN) return;
  int l = threadIdx.x & 63;
  int c16 = l & 15, eg = l >> 4;
  int beg = rp[node], deg = rp[node + 1] - beg;
  float acc[8] = {0.f,0.f,0.f,0.f,0.f,0.f,0.f,0.f};
  const ushort* fbase = feat + c16 * 8;

  for(int base = 0; base < deg; base += 64){
    int nchunk = min(deg - base, 64);
    int idx = col[beg + base + min(l, nchunk - 1)];
#pragma unroll 2
    for(int j = 0; j < nchunk; j += 4){
      int e = j + eg;
      int s = __shfl(idx, min(e, nchunk - 1));
      uint4 v = *(const uint4*)(fbase + (size_t)s * FDIM);
      if(e < nchunk){
        acc[0] += bflo(v.x); acc[1] += bfhi(v.x);
        acc[2] += bflo(v.y); acc[3] += bfhi(v.y);
        acc[4] += bflo(v.z); acc[5] += bfhi(v.z);
        acc[6] += bflo(v.w); acc[7] += bfhi(v.w);
      }
    }
  }
  // reduce the 4 edge-slot groups (lanes l, l+16, l+32, l+48)
#pragma unroll
  for(int i = 0; i < 8; ++i){
    acc[i] += __shfl_xor(acc[i], 16);
    acc[i] += __shfl_xor(acc[i], 32);
  }
  if(eg == 0){
    float inv = 1.0f / (float)max(deg, 1);
    uint4 o;
    o.x = (uint)f2bf(acc[0] * inv) | ((uint)f2bf(acc[1] * inv) << 16);
    o.y = (uint)f2bf(acc[2] * inv) | ((uint)f2bf(acc[3] * inv) << 16);
    o.z = (uint)f2bf(acc[4] * inv) | ((uint)f2bf(acc[5] * inv) << 16);
    o.w = (uint)f2bf(acc[6] * inv) | ((uint)f2bf(acc[7] * inv) << 16);
    *(uint4*)(mean + (size_t)node * FDIM + c16 * 8) = o;
  }
}

// ---------- fused linear: out = relu(A1@Wl^T + b + A2@Wr^T), 128 outputs ----------
// block = 256 (4 waves); wave g owns cols [32g,32g+32); blockIdx = worker, 5 strips of 16 rows
__launch_bounds__(256)
__global__ void k_lin128(const ushort* __restrict__ A1, const ushort* __restrict__ A2,
                         const float* __restrict__ Wl, const float* __restrict__ Wr,
                         const float* __restrict__ bias, ushort* __restrict__ out){
  int g = threadIdx.x >> 6;
  int l = threadIdx.x & 63;
  int worker = blockIdx.x;
  int r16 = l & 15, q = l >> 4;

  BF8 bl[2][4], br[2][4];
#pragma unroll
  for(int tt = 0; tt < 2; ++tt){
    int colw = 32 * g + 16 * tt + r16;
    const float* pl = Wl + colw * FDIM + q * 8;
    const float* pr = Wr + colw * FDIM + q * 8;
#pragma unroll
    for(int ks = 0; ks < 4; ++ks){
      float4 x0 = *(const float4*)(pl + 32 * ks);
      float4 x1 = *(const float4*)(pl + 32 * ks + 4);
      BF8 t;
      t.s[0]=f2bf(x0.x); t.s[1]=f2bf(x0.y); t.s[2]=f2bf(x0.z); t.s[3]=f2bf(x0.w);
      t.s[4]=f2bf(x1.x); t.s[5]=f2bf(x1.y); t.s[6]=f2bf(x1.z); t.s[7]=f2bf(x1.w);
      bl[tt][ks] = t;
      float4 y0 = *(const float4*)(pr + 32 * ks);
      float4 y1 = *(const float4*)(pr + 32 * ks + 4);
      BF8 u;
      u.s[0]=f2bf(y0.x); u.s[1]=f2bf(y0.y); u.s[2]=f2bf(y0.z); u.s[3]=f2bf(y0.w);
      u.s[4]=f2bf(y1.x); u.s[5]=f2bf(y1.y); u.s[6]=f2bf(y1.z); u.s[7]=f2bf(y1.w);
      br[tt][ks] = u;
    }
  }
  float bv0 = bias[32 * g + r16];
  float bv1 = bias[32 * g + 16 + r16];

  for(int s = 0; s < 5; ++s){
    int m0 = (worker * 5 + s) * 16;
    BF8 a1[4], a2[4];
    const ushort* p1 = A1 + (size_t)(m0 + r16) * FDIM + q * 8;
    const ushort* p2 = A2 + (size_t)(m0 + r16) * FDIM + q * 8;
#pragma unroll
    for(int ks = 0; ks < 4; ++ks){
      a1[ks].u = *(const uint4*)(p1 + 32 * ks);
      a2[ks].u = *(const uint4*)(p2 + 32 * ks);
    }
    f32x4 acc0 = {0.f,0.f,0.f,0.f}, acc1 = {0.f,0.f,0.f,0.f};
#pragma unroll
    for(int ks = 0; ks < 4; ++ks){
      acc0 = __builtin_amdgcn_mfma_f32_16x16x32_bf16(a1[ks].v, bl[0][ks].v, acc0, 0, 0, 0);
      acc0 = __builtin_amdgcn_mfma_f32_16x16x32_bf16(a2[ks].v, br[0][ks].v, acc0, 0, 0, 0);
      acc1 = __builtin_amdgcn_mfma_f32_16x16x32_bf16(a1[ks].v, bl[1][ks].v, acc1, 0, 0, 0);
      acc1 = __builtin_amdgcn_mfma_f32_16x16x32_bf16(a2[ks].v, br[1][ks].v, acc1, 0, 0, 0);
    }
#pragma unroll
    for(int r = 0; r < 4; ++r){
      int row = m0 + q * 4 + r;
      float v0 = fmaxf(acc0[r] + bv0, 0.f);
      float v1 = fmaxf(acc1[r] + bv1, 0.f);
      out[(size_t)row * FDIM + 32 * g + r16]      = f2bf(v0);
      out[(size_t)row * FDIM + 32 * g + 16 + r16] = f2bf(v1);
    }
  }
}

// ---------- layer-3 linear (40 outputs) + fused log_softmax ----------
// block = 192 (3 waves); wave g owns cols [16g,16g+16) masked at 40.
// Per 16-row strip: z -> LDS, 16 threads compute lse, all threads write out.
__launch_bounds__(192)
__global__ void k_lin40(const ushort* __restrict__ A1, const ushort* __restrict__ A2,
                        const float* __restrict__ Wl, const float* __restrict__ Wr,
                        const float* __restrict__ bias, float* __restrict__ out){
  int g = threadIdx.x >> 6;
  int l = threadIdx.x & 63;
  int t = threadIdx.x;
  int worker = blockIdx.x;
  int r16 = l & 15, q = l >> 4;
  int colw = 16 * g + r16;
  bool vcol = colw < FOUT;

  __shared__ float zs[16][44];   // cols 0..39 = z, col 40 = lse

  BF8 bl[4], br[4];
#pragma unroll
  for(int ks = 0; ks < 4; ++ks){
    BF8 tt, u;
    if(vcol){
      const float* pl = Wl + colw * FDIM + q * 8 + 32 * ks;
      const float* pr = Wr + colw * FDIM + q * 8 + 32 * ks;
      float4 x0 = ((const float4*)pl)[0], x1 = ((const float4*)pl)[1];
      tt.s[0]=f2bf(x0.x); tt.s[1]=f2bf(x0.y); tt.s[2]=f2bf(x0.z); tt.s[3]=f2bf(x0.w);
      tt.s[4]=f2bf(x1.x); tt.s[5]=f2bf(x1.y); tt.s[6]=f2bf(x1.z); tt.s[7]=f2bf(x1.w);
      float4 y0 = ((const float4*)pr)[0], y1 = ((const float4*)pr)[1];
      u.s[0]=f2bf(y0.x); u.s[1]=f2bf(y0.y); u.s[2]=f2bf(y0.z); u.s[3]=f2bf(y0.w);
      u.s[4]=f2bf(y1.x); u.s[5]=f2bf(y1.y); u.s[6]=f2bf(y1.z); u.s[7]=f2bf(y1.w);
    } else {
      tt.u = make_uint4(0,0,0,0);
      u.u = make_uint4(0,0,0,0);
    }
    bl[ks] = tt; br[ks] = u;
  }
  float bv = vcol ? bias[colw] : 0.f;

  for(int s = 0; s < 5; ++s){
    int m0 = (worker * 5 + s) * 16;
    BF8 a1[4], a2[4];
    const ushort* p1 = A1 + (size_t)(m0 + r16) * FDIM + q * 8;
    const ushort* p2 = A2 + (size_t)(m0 + r16) * FDIM + q * 8;
#pragma unroll
    for(int ks = 0; ks < 4; ++ks){
      a1[ks].u = *(const uint4*)(p1 + 32 * ks);
      a2[ks].u = *(const uint4*)(p2 + 32 * ks);
    }
    f32x4 acc = {0.f,0.f,0.f,0.f};
#pragma unroll
    for(int ks = 0; ks < 4; ++ks){
      acc = __builtin_amdgcn_mfma_f32_16x16x32_bf16(a1[ks].v, bl[ks].v, acc, 0, 0, 0);
      acc = __builtin_amdgcn_mfma_f32_16x16x32_bf16(a2[ks].v, br[ks].v, acc, 0, 0, 0);
    }
    if(vcol){
#pragma unroll
      for(int r = 0; r < 4; ++r) zs[q * 4 + r][colw] = acc[r] + bv;
    }
    __syncthreads();
    if(t < 16){
      float m = zs[t][0];
#pragma unroll
      for(int i = 1; i < FOUT; ++i) m = fmaxf(m, zs[t][i]);
      float ssum = 0.f;
#pragma unroll
      for(int i = 0; i < FOUT; ++i) ssum += __expf(zs[t][i] - m);
      zs[t][40] = m + __logf(ssum);
    }
    __syncthreads();
    for(int u = t; u < 16 * FOUT; u += 192){
      int row = u / FOUT, c = u - row * FOUT;
      out[(size_t)(m0 + row) * FOUT + c] = zs[row][c] - zs[row][40];
    }
    __syncthreads();
  }
}

extern "C" void kernel_launch(void* const* d_in, const int* in_sizes, int n_in,
                              void* d_out, int out_size, void* d_ws, size_t ws_size,
                              hipStream_t stream){
  const float* x   = (const float*)d_in[0];
  const void*  edges = d_in[1];
  const float* W1l = (const float*)d_in[2];
  const float* b1  = (const float*)d_in[3];
  const float* W1r = (const float*)d_in[4];
  const float* W2l = (const float*)d_in[5];
  const float* b2  = (const float*)d_in[6];
  const float* W2r = (const float*)d_in[7];
  const float* W3l = (const float*)d_in[8];
  const float* b3  = (const float*)d_in[9];
  const float* W3r = (const float*)d_in[10];
  float* out = (float*)d_out;

  char* ws = (char*)d_ws;
  size_t off = 0;
  auto alloc = [&](size_t bytes)->void*{
    void* p = ws + off;
    off += (bytes + 255) & ~(size_t)255;
    return p;
  };
  ushort* xb   = (ushort*)alloc((size_t)NN * FDIM * 2);
  ushort* h1   = (ushort*)alloc((size_t)NN * FDIM * 2);
  ushort* h2   = (ushort*)alloc((size_t)NN * FDIM * 2);
  ushort* mean = (ushort*)alloc((size_t)NN * FDIM * 2);
  int*    deg  = (int*)alloc((size_t)NN * 4);        // reused as cursor
  int*    rp   = (int*)alloc((size_t)(NN + 1) * 4);
  int*    col  = (int*)alloc((size_t)NE * 4);
  int*    bsum = (int*)alloc(1024);
  int*    flag = (int*)alloc(256);

  hipMemsetAsync(deg, 0, (size_t)NN * 4, stream);
  k_detect<<<1, 64, 0, stream>>>((const unsigned long long*)edges, flag);
  k_cvt<<<(NN * FDIM / 4 + 255) / 256, 256, 0, stream>>>((const float4*)x, (ushort4*)xb, NN * FDIM / 4);
  k_count<<<(NE + 255) / 256, 256, 0, stream>>>(edges, flag, deg);
  int nb = (NN + 255) / 256;  // 196
  k_scan1<<<nb, 256, 0, stream>>>(deg, rp, bsum);
  k_scan2<<<1, 256, 0, stream>>>(bsum, nb);
  k_scan3<<<nb, 256, 0, stream>>>(rp, bsum);
  hipMemsetAsync(deg, 0, (size_t)NN * 4, stream);
  k_fill<<<(NE + 255) / 256, 256, 0, stream>>>(edges, flag, rp, deg, col);

  // layer 1
  k_agg<<<(NN * 64 + 255) / 256, 256, 0, stream>>>(xb, rp, col, mean);
  k_lin128<<<625, 256, 0, stream>>>(mean, xb, W1l, W1r, b1, h1);
  // layer 2
  k_agg<<<(NN * 64 + 255) / 256, 256, 0, stream>>>(h1, rp, col, mean);
  k_lin128<<<625, 256, 0, stream>>>(mean, h1, W2l, W2r, b2, h2);
  // layer 3
  k_agg<<<(NN * 64 + 255) / 256, 256, 0, stream>>>(h2, rp, col, mean);
  k_lin40<<<625, 192, 0, stream>>>(mean, h2, W3l, W3r, b3, out);
}

// Round 3
// 242.176 us; speedup vs baseline: 1.2210x; 1.0079x over previous
//
#include <hip/hip_runtime.h>

#define NN 50000
#define NE 640000
#define FDIM 128
#define FOUT 40

typedef unsigned int uint;
typedef unsigned short ushort;
typedef __attribute__((ext_vector_type(8))) __bf16 bf16x8;
typedef __attribute__((ext_vector_type(4))) float f32x4;

union BF8 { bf16x8 v; uint4 u; ushort s[8]; };

__device__ __forceinline__ ushort f2bf(float f){
  uint b = __float_as_uint(f);
  b += 0x7fffu + ((b >> 16) & 1u);   // RNE; inputs never NaN/Inf here
  return (ushort)(b >> 16);
}
__device__ __forceinline__ float bflo(uint v){ return __uint_as_float(v << 16); }
__device__ __forceinline__ float bfhi(uint v){ return __uint_as_float(v & 0xffff0000u); }

// ---------- zero deg + dtype detect (edges int64 (ref) vs int32) ----------
__global__ void k_zero_detect(const unsigned long long* __restrict__ e64,
                              int* __restrict__ flag, int* __restrict__ deg){
  int i = blockIdx.x * blockDim.x + threadIdx.x;
  if(i < NN) deg[i] = 0;
  if(blockIdx.x == 0 && threadIdx.x < 64){
    unsigned long long v = e64[threadIdx.x];
    int ok = (int)__all(v < 4294967296ULL);  // all-small => genuinely int64 data
    if(threadIdx.x == 0) *flag = ok;
  }
}
__device__ __forceinline__ int get_edge(const void* ep, int is64, int idx){
  return is64 ? (int)(((const long long*)ep)[idx]) : ((const int*)ep)[idx];
}

// ---------- f32 -> bf16 convert ----------
__global__ void k_cvt(const float4* __restrict__ in, ushort4* __restrict__ out, int n4){
  int i = blockIdx.x * blockDim.x + threadIdx.x;
  if(i >= n4) return;
  float4 v = in[i];
  ushort4 o; o.x = f2bf(v.x); o.y = f2bf(v.y); o.z = f2bf(v.z); o.w = f2bf(v.w);
  out[i] = o;
}

// ---------- CSR build ----------
__global__ void k_count(const void* __restrict__ edges, const int* __restrict__ flag,
                        int* __restrict__ deg){
  int e = blockIdx.x * blockDim.x + threadIdx.x;
  if(e >= NE) return;
  int is64 = *flag;
  int d = get_edge(edges, is64, NE + e);
  atomicAdd(&deg[d], 1);
}

__global__ void k_scan1(const int* __restrict__ deg, int* __restrict__ rp, int* __restrict__ bsum){
  __shared__ int s[256];
  int t = threadIdx.x;
  int i = blockIdx.x * 256 + t;
  int v = (i < NN) ? deg[i] : 0;
  s[t] = v; __syncthreads();
  for(int off = 1; off < 256; off <<= 1){
    int a = (t >= off) ? s[t - off] : 0;
    __syncthreads();
    s[t] += a;
    __syncthreads();
  }
  if(i < NN) rp[i] = s[t] - v;           // exclusive within block
  if(t == 255) bsum[blockIdx.x] = s[255];
}

__global__ void k_scan2(int* __restrict__ bsum, int nb){
  __shared__ int s[256];
  int t = threadIdx.x;
  int v = (t < nb) ? bsum[t] : 0;
  s[t] = v; __syncthreads();
  for(int off = 1; off < 256; off <<= 1){
    int a = (t >= off) ? s[t - off] : 0;
    __syncthreads();
    s[t] += a;
    __syncthreads();
  }
  if(t < nb) bsum[t] = s[t] - v;         // exclusive block offsets
}

// also zeros the fill cursor (deg buffer reuse) — k_scan1 already consumed deg
__global__ void k_scan3(int* __restrict__ rp, const int* __restrict__ bsum,
                        int* __restrict__ cur){
  int i = blockIdx.x * 256 + threadIdx.x;
  if(i < NN){ rp[i] += bsum[blockIdx.x]; cur[i] = 0; }
  if(i == 0) rp[NN] = NE;
}

__global__ void k_fill(const void* __restrict__ edges, const int* __restrict__ flag,
                       const int* __restrict__ rp, int* __restrict__ cur, int* __restrict__ col){
  int e = blockIdx.x * blockDim.x + threadIdx.x;
  if(e >= NE) return;
  int is64 = *flag;
  int d = get_edge(edges, is64, NE + e);
  int s = get_edge(edges, is64, e);
  int p = rp[d] + atomicAdd(&cur[d], 1);
  col[p] = s;
}

// ---------- mean aggregation: one wave per node ----------
// lanes = 16 feature-chunks x 4 edge-slots: lane l reads the 16B chunk (l&15)
// of the row for edge j+(l>>4). Edge indices preloaded 64-wide and distributed
// via shfl -> all gathers in the degree loop are independent.
__global__ void k_agg(const ushort* __restrict__ feat, const int* __restrict__ rp,
                      const int* __restrict__ col, ushort* __restrict__ mean){
  int node = (blockIdx.x * blockDim.x + threadIdx.x) >> 6;
  if(node >= NN) return;
  int l = threadIdx.x & 63;
  int c16 = l & 15, eg = l >> 4;
  int beg = rp[node], deg = rp[node + 1] - beg;
  float acc[8] = {0.f,0.f,0.f,0.f,0.f,0.f,0.f,0.f};
  const ushort* fbase = feat + c16 * 8;

  for(int base = 0; base < deg; base += 64){
    int nchunk = min(deg - base, 64);
    int idx = col[beg + base + min(l, nchunk - 1)];
#pragma unroll 2
    for(int j = 0; j < nchunk; j += 4){
      int e = j + eg;
      int s = __shfl(idx, min(e, nchunk - 1));
      uint4 v = *(const uint4*)(fbase + (size_t)s * FDIM);
      if(e < nchunk){
        acc[0] += bflo(v.x); acc[1] += bfhi(v.x);
        acc[2] += bflo(v.y); acc[3] += bfhi(v.y);
        acc[4] += bflo(v.z); acc[5] += bfhi(v.z);
        acc[6] += bflo(v.w); acc[7] += bfhi(v.w);
      }
    }
  }
  // reduce the 4 edge-slot groups (lanes l, l+16, l+32, l+48)
#pragma unroll
  for(int i = 0; i < 8; ++i){
    acc[i] += __shfl_xor(acc[i], 16);
    acc[i] += __shfl_xor(acc[i], 32);
  }
  if(eg == 0){
    float inv = 1.0f / (float)max(deg, 1);
    uint4 o;
    o.x = (uint)f2bf(acc[0] * inv) | ((uint)f2bf(acc[1] * inv) << 16);
    o.y = (uint)f2bf(acc[2] * inv) | ((uint)f2bf(acc[3] * inv) << 16);
    o.z = (uint)f2bf(acc[4] * inv) | ((uint)f2bf(acc[5] * inv) << 16);
    o.w = (uint)f2bf(acc[6] * inv) | ((uint)f2bf(acc[7] * inv) << 16);
    *(uint4*)(mean + (size_t)node * FDIM + c16 * 8) = o;
  }
}

// ---------- fused linear: out = relu(A1@Wl^T + b + A2@Wr^T), 128 outputs ----------
// block = 256 (4 waves); wave g owns cols [32g,32g+32); blockIdx = worker, 5 strips of 16 rows
__launch_bounds__(256)
__global__ void k_lin128(const ushort* __restrict__ A1, const ushort* __restrict__ A2,
                         const float* __restrict__ Wl, const float* __restrict__ Wr,
                         const float* __restrict__ bias, ushort* __restrict__ out){
  int g = threadIdx.x >> 6;
  int l = threadIdx.x & 63;
  int worker = blockIdx.x;
  int r16 = l & 15, q = l >> 4;

  BF8 bl[2][4], br[2][4];
#pragma unroll
  for(int tt = 0; tt < 2; ++tt){
    int colw = 32 * g + 16 * tt + r16;
    const float* pl = Wl + colw * FDIM + q * 8;
    const float* pr = Wr + colw * FDIM + q * 8;
#pragma unroll
    for(int ks = 0; ks < 4; ++ks){
      float4 x0 = *(const float4*)(pl + 32 * ks);
      float4 x1 = *(const float4*)(pl + 32 * ks + 4);
      BF8 t;
      t.s[0]=f2bf(x0.x); t.s[1]=f2bf(x0.y); t.s[2]=f2bf(x0.z); t.s[3]=f2bf(x0.w);
      t.s[4]=f2bf(x1.x); t.s[5]=f2bf(x1.y); t.s[6]=f2bf(x1.z); t.s[7]=f2bf(x1.w);
      bl[tt][ks] = t;
      float4 y0 = *(const float4*)(pr + 32 * ks);
      float4 y1 = *(const float4*)(pr + 32 * ks + 4);
      BF8 u;
      u.s[0]=f2bf(y0.x); u.s[1]=f2bf(y0.y); u.s[2]=f2bf(y0.z); u.s[3]=f2bf(y0.w);
      u.s[4]=f2bf(y1.x); u.s[5]=f2bf(y1.y); u.s[6]=f2bf(y1.z); u.s[7]=f2bf(y1.w);
      br[tt][ks] = u;
    }
  }
  float bv0 = bias[32 * g + r16];
  float bv1 = bias[32 * g + 16 + r16];

  for(int s = 0; s < 5; ++s){
    int m0 = (worker * 5 + s) * 16;
    BF8 a1[4], a2[4];
    const ushort* p1 = A1 + (size_t)(m0 + r16) * FDIM + q * 8;
    const ushort* p2 = A2 + (size_t)(m0 + r16) * FDIM + q * 8;
#pragma unroll
    for(int ks = 0; ks < 4; ++ks){
      a1[ks].u = *(const uint4*)(p1 + 32 * ks);
      a2[ks].u = *(const uint4*)(p2 + 32 * ks);
    }
    f32x4 acc0 = {0.f,0.f,0.f,0.f}, acc1 = {0.f,0.f,0.f,0.f};
#pragma unroll
    for(int ks = 0; ks < 4; ++ks){
      acc0 = __builtin_amdgcn_mfma_f32_16x16x32_bf16(a1[ks].v, bl[0][ks].v, acc0, 0, 0, 0);
      acc0 = __builtin_amdgcn_mfma_f32_16x16x32_bf16(a2[ks].v, br[0][ks].v, acc0, 0, 0, 0);
      acc1 = __builtin_amdgcn_mfma_f32_16x16x32_bf16(a1[ks].v, bl[1][ks].v, acc1, 0, 0, 0);
      acc1 = __builtin_amdgcn_mfma_f32_16x16x32_bf16(a2[ks].v, br[1][ks].v, acc1, 0, 0, 0);
    }
#pragma unroll
    for(int r = 0; r < 4; ++r){
      int row = m0 + q * 4 + r;
      float v0 = fmaxf(acc0[r] + bv0, 0.f);
      float v1 = fmaxf(acc1[r] + bv1, 0.f);
      out[(size_t)row * FDIM + 32 * g + r16]      = f2bf(v0);
      out[(size_t)row * FDIM + 32 * g + 16 + r16] = f2bf(v1);
    }
  }
}

// ---------- layer-3 linear (40 outputs) + fused log_softmax ----------
// block = 192 (3 waves); wave g owns cols [16g,16g+16) masked at 40.
// Per 16-row strip: z -> LDS, 16 threads compute lse, all threads write out.
__launch_bounds__(192)
__global__ void k_lin40(const ushort* __restrict__ A1, const ushort* __restrict__ A2,
                        const float* __restrict__ Wl, const float* __restrict__ Wr,
                        const float* __restrict__ bias, float* __restrict__ out){
  int g = threadIdx.x >> 6;
  int l = threadIdx.x & 63;
  int t = threadIdx.x;
  int worker = blockIdx.x;
  int r16 = l & 15, q = l >> 4;
  int colw = 16 * g + r16;
  bool vcol = colw < FOUT;

  __shared__ float zs[16][44];   // cols 0..39 = z, col 40 = lse

  BF8 bl[4], br[4];
#pragma unroll
  for(int ks = 0; ks < 4; ++ks){
    BF8 tt, u;
    if(vcol){
      const float* pl = Wl + colw * FDIM + q * 8 + 32 * ks;
      const float* pr = Wr + colw * FDIM + q * 8 + 32 * ks;
      float4 x0 = ((const float4*)pl)[0], x1 = ((const float4*)pl)[1];
      tt.s[0]=f2bf(x0.x); tt.s[1]=f2bf(x0.y); tt.s[2]=f2bf(x0.z); tt.s[3]=f2bf(x0.w);
      tt.s[4]=f2bf(x1.x); tt.s[5]=f2bf(x1.y); tt.s[6]=f2bf(x1.z); tt.s[7]=f2bf(x1.w);
      float4 y0 = ((const float4*)pr)[0], y1 = ((const float4*)pr)[1];
      u.s[0]=f2bf(y0.x); u.s[1]=f2bf(y0.y); u.s[2]=f2bf(y0.z); u.s[3]=f2bf(y0.w);
      u.s[4]=f2bf(y1.x); u.s[5]=f2bf(y1.y); u.s[6]=f2bf(y1.z); u.s[7]=f2bf(y1.w);
    } else {
      tt.u = make_uint4(0,0,0,0);
      u.u = make_uint4(0,0,0,0);
    }
    bl[ks] = tt; br[ks] = u;
  }
  float bv = vcol ? bias[colw] : 0.f;

  for(int s = 0; s < 5; ++s){
    int m0 = (worker * 5 + s) * 16;
    BF8 a1[4], a2[4];
    const ushort* p1 = A1 + (size_t)(m0 + r16) * FDIM + q * 8;
    const ushort* p2 = A2 + (size_t)(m0 + r16) * FDIM + q * 8;
#pragma unroll
    for(int ks = 0; ks < 4; ++ks){
      a1[ks].u = *(const uint4*)(p1 + 32 * ks);
      a2[ks].u = *(const uint4*)(p2 + 32 * ks);
    }
    f32x4 acc = {0.f,0.f,0.f,0.f};
#pragma unroll
    for(int ks = 0; ks < 4; ++ks){
      acc = __builtin_amdgcn_mfma_f32_16x16x32_bf16(a1[ks].v, bl[ks].v, acc, 0, 0, 0);
      acc = __builtin_amdgcn_mfma_f32_16x16x32_bf16(a2[ks].v, br[ks].v, acc, 0, 0, 0);
    }
    if(vcol){
#pragma unroll
      for(int r = 0; r < 4; ++r) zs[q * 4 + r][colw] = acc[r] + bv;
    }
    __syncthreads();
    if(t < 16){
      float m = zs[t][0];
#pragma unroll
      for(int i = 1; i < FOUT; ++i) m = fmaxf(m, zs[t][i]);
      float ssum = 0.f;
#pragma unroll
      for(int i = 0; i < FOUT; ++i) ssum += __expf(zs[t][i] - m);
      zs[t][40] = m + __logf(ssum);
    }
    __syncthreads();
    for(int u = t; u < 16 * FOUT; u += 192){
      int row = u / FOUT, c = u - row * FOUT;
      out[(size_t)(m0 + row) * FOUT + c] = zs[row][c] - zs[row][40];
    }
    __syncthreads();
  }
}

extern "C" void kernel_launch(void* const* d_in, const int* in_sizes, int n_in,
                              void* d_out, int out_size, void* d_ws, size_t ws_size,
                              hipStream_t stream){
  const float* x   = (const float*)d_in[0];
  const void*  edges = d_in[1];
  const float* W1l = (const float*)d_in[2];
  const float* b1  = (const float*)d_in[3];
  const float* W1r = (const float*)d_in[4];
  const float* W2l = (const float*)d_in[5];
  const float* b2  = (const float*)d_in[6];
  const float* W2r = (const float*)d_in[7];
  const float* W3l = (const float*)d_in[8];
  const float* b3  = (const float*)d_in[9];
  const float* W3r = (const float*)d_in[10];
  float* out = (float*)d_out;

  char* ws = (char*)d_ws;
  size_t off = 0;
  auto alloc = [&](size_t bytes)->void*{
    void* p = ws + off;
    off += (bytes + 255) & ~(size_t)255;
    return p;
  };
  ushort* xb   = (ushort*)alloc((size_t)NN * FDIM * 2);
  ushort* h1   = (ushort*)alloc((size_t)NN * FDIM * 2);
  ushort* h2   = (ushort*)alloc((size_t)NN * FDIM * 2);
  ushort* mean = (ushort*)alloc((size_t)NN * FDIM * 2);
  int*    deg  = (int*)alloc((size_t)NN * 4);        // reused as cursor
  int*    rp   = (int*)alloc((size_t)(NN + 1) * 4);
  int*    col  = (int*)alloc((size_t)NE * 4);
  int*    bsum = (int*)alloc(1024);
  int*    flag = (int*)alloc(256);

  k_zero_detect<<<(NN + 255) / 256, 256, 0, stream>>>((const unsigned long long*)edges, flag, deg);
  k_cvt<<<(NN * FDIM / 4 + 255) / 256, 256, 0, stream>>>((const float4*)x, (ushort4*)xb, NN * FDIM / 4);
  k_count<<<(NE + 255) / 256, 256, 0, stream>>>(edges, flag, deg);
  int nb = (NN + 255) / 256;  // 196
  k_scan1<<<nb, 256, 0, stream>>>(deg, rp, bsum);
  k_scan2<<<1, 256, 0, stream>>>(bsum, nb);
  k_scan3<<<nb, 256, 0, stream>>>(rp, bsum, deg);
  k_fill<<<(NE + 255) / 256, 256, 0, stream>>>(edges, flag, rp, deg, col);

  // layer 1
  k_agg<<<(NN * 64 + 255) / 256, 256, 0, stream>>>(xb, rp, col, mean);
  k_lin128<<<625, 256, 0, stream>>>(mean, xb, W1l, W1r, b1, h1);
  // layer 2
  k_agg<<<(NN * 64 + 255) / 256, 256, 0, stream>>>(h1, rp, col, mean);
  k_lin128<<<625, 256, 0, stream>>>(mean, h1, W2l, W2r, b2, h2);
  // layer 3
  k_agg<<<(NN * 64 + 255) / 256, 256, 0, stream>>>(h2, rp, col, mean);
  k_lin40<<<625, 192, 0, stream>>>(mean, h2, W3l, W3r, b3, out);
}

// Round 4
// 232.165 us; speedup vs baseline: 1.2736x; 1.0431x over previous
//
#include <hip/hip_runtime.h>

#define NN 50000
#define NE 640000
#define FDIM 128
#define FOUT 40

typedef unsigned int uint;
typedef unsigned short ushort;
typedef __attribute__((ext_vector_type(8))) __bf16 bf16x8;
typedef __attribute__((ext_vector_type(4))) float f32x4;

union BF8 { bf16x8 v; uint4 u; ushort s[8]; };

__device__ __forceinline__ ushort f2bf(float f){
  uint b = __float_as_uint(f);
  b += 0x7fffu + ((b >> 16) & 1u);   // RNE; inputs never NaN/Inf here
  return (ushort)(b >> 16);
}
__device__ __forceinline__ float bflo(uint v){ return __uint_as_float(v << 16); }
__device__ __forceinline__ float bfhi(uint v){ return __uint_as_float(v & 0xffff0000u); }

// ---------- zero deg + dtype detect (edges int64 (ref) vs int32) ----------
__global__ void k_zero_detect(const unsigned long long* __restrict__ e64,
                              int* __restrict__ flag, int* __restrict__ deg){
  int i = blockIdx.x * blockDim.x + threadIdx.x;
  if(i < NN) deg[i] = 0;
  if(blockIdx.x == 0 && threadIdx.x < 64){
    unsigned long long v = e64[threadIdx.x];
    int ok = (int)__all(v < 4294967296ULL);  // all-small => genuinely int64 data
    if(threadIdx.x == 0) *flag = ok;
  }
}
__device__ __forceinline__ int get_edge(const void* ep, int is64, int idx){
  return is64 ? (int)(((const long long*)ep)[idx]) : ((const int*)ep)[idx];
}

// ---------- CSR build ----------
__global__ void k_count(const void* __restrict__ edges, const int* __restrict__ flag,
                        int* __restrict__ deg){
  int e = blockIdx.x * blockDim.x + threadIdx.x;
  if(e >= NE) return;
  int is64 = *flag;
  int d = get_edge(edges, is64, NE + e);
  atomicAdd(&deg[d], 1);
}

__global__ void k_scan1(const int* __restrict__ deg, int* __restrict__ rp, int* __restrict__ bsum){
  __shared__ int s[256];
  int t = threadIdx.x;
  int i = blockIdx.x * 256 + t;
  int v = (i < NN) ? deg[i] : 0;
  s[t] = v; __syncthreads();
  for(int off = 1; off < 256; off <<= 1){
    int a = (t >= off) ? s[t - off] : 0;
    __syncthreads();
    s[t] += a;
    __syncthreads();
  }
  if(i < NN) rp[i] = s[t] - v;           // exclusive within block
  if(t == 255) bsum[blockIdx.x] = s[255];
}

__global__ void k_scan2(int* __restrict__ bsum, int nb){
  __shared__ int s[256];
  int t = threadIdx.x;
  int v = (t < nb) ? bsum[t] : 0;
  s[t] = v; __syncthreads();
  for(int off = 1; off < 256; off <<= 1){
    int a = (t >= off) ? s[t - off] : 0;
    __syncthreads();
    s[t] += a;
    __syncthreads();
  }
  if(t < nb) bsum[t] = s[t] - v;         // exclusive block offsets
}

// also zeros the fill cursor (deg buffer reuse) — k_scan1 already consumed deg
__global__ void k_scan3(int* __restrict__ rp, const int* __restrict__ bsum,
                        int* __restrict__ cur){
  int i = blockIdx.x * 256 + threadIdx.x;
  if(i < NN){ rp[i] += bsum[blockIdx.x]; cur[i] = 0; }
  if(i == 0) rp[NN] = NE;
}

__global__ void k_fill(const void* __restrict__ edges, const int* __restrict__ flag,
                       const int* __restrict__ rp, int* __restrict__ cur, int* __restrict__ col){
  int e = blockIdx.x * blockDim.x + threadIdx.x;
  if(e >= NE) return;
  int is64 = *flag;
  int d = get_edge(edges, is64, NE + e);
  int s = get_edge(edges, is64, e);
  int p = rp[d] + atomicAdd(&cur[d], 1);
  col[p] = s;
}

// ---------- A-kernel (layers 1,2): u = in@Wl^T (bf16), v = in@Wr^T + b (bf16) ----------
// block = 256 (4 waves); wave g owns cols [32g,32g+32); grid 625, 5 strips of 16 rows
__launch_bounds__(256)
__global__ void k_linuv(const float* __restrict__ inF, const ushort* __restrict__ inB,
                        int use_f32,
                        const float* __restrict__ Wl, const float* __restrict__ Wr,
                        const float* __restrict__ bias,
                        ushort* __restrict__ u, ushort* __restrict__ v){
  int g = threadIdx.x >> 6;
  int l = threadIdx.x & 63;
  int worker = blockIdx.x;
  int r16 = l & 15, q = l >> 4;

  BF8 bl[2][4], br[2][4];
#pragma unroll
  for(int tt = 0; tt < 2; ++tt){
    int colw = 32 * g + 16 * tt + r16;
    const float* pl = Wl + colw * FDIM + q * 8;
    const float* pr = Wr + colw * FDIM + q * 8;
#pragma unroll
    for(int ks = 0; ks < 4; ++ks){
      float4 x0 = *(const float4*)(pl + 32 * ks);
      float4 x1 = *(const float4*)(pl + 32 * ks + 4);
      BF8 t;
      t.s[0]=f2bf(x0.x); t.s[1]=f2bf(x0.y); t.s[2]=f2bf(x0.z); t.s[3]=f2bf(x0.w);
      t.s[4]=f2bf(x1.x); t.s[5]=f2bf(x1.y); t.s[6]=f2bf(x1.z); t.s[7]=f2bf(x1.w);
      bl[tt][ks] = t;
      float4 y0 = *(const float4*)(pr + 32 * ks);
      float4 y1 = *(const float4*)(pr + 32 * ks + 4);
      BF8 w;
      w.s[0]=f2bf(y0.x); w.s[1]=f2bf(y0.y); w.s[2]=f2bf(y0.z); w.s[3]=f2bf(y0.w);
      w.s[4]=f2bf(y1.x); w.s[5]=f2bf(y1.y); w.s[6]=f2bf(y1.z); w.s[7]=f2bf(y1.w);
      br[tt][ks] = w;
    }
  }
  float bv0 = bias[32 * g + r16];
  float bv1 = bias[32 * g + 16 + r16];

  for(int s = 0; s < 5; ++s){
    int m0 = (worker * 5 + s) * 16;
    BF8 a[4];
    if(use_f32){
      const float* pf = inF + (size_t)(m0 + r16) * FDIM + q * 8;
#pragma unroll
      for(int ks = 0; ks < 4; ++ks){
        float4 x0 = *(const float4*)(pf + 32 * ks);
        float4 x1 = *(const float4*)(pf + 32 * ks + 4);
        BF8 t;
        t.s[0]=f2bf(x0.x); t.s[1]=f2bf(x0.y); t.s[2]=f2bf(x0.z); t.s[3]=f2bf(x0.w);
        t.s[4]=f2bf(x1.x); t.s[5]=f2bf(x1.y); t.s[6]=f2bf(x1.z); t.s[7]=f2bf(x1.w);
        a[ks] = t;
      }
    } else {
      const ushort* pb = inB + (size_t)(m0 + r16) * FDIM + q * 8;
#pragma unroll
      for(int ks = 0; ks < 4; ++ks) a[ks].u = *(const uint4*)(pb + 32 * ks);
    }
    f32x4 aU0 = {0,0,0,0}, aU1 = {0,0,0,0}, aV0 = {0,0,0,0}, aV1 = {0,0,0,0};
#pragma unroll
    for(int ks = 0; ks < 4; ++ks){
      aU0 = __builtin_amdgcn_mfma_f32_16x16x32_bf16(a[ks].v, bl[0][ks].v, aU0, 0, 0, 0);
      aV0 = __builtin_amdgcn_mfma_f32_16x16x32_bf16(a[ks].v, br[0][ks].v, aV0, 0, 0, 0);
      aU1 = __builtin_amdgcn_mfma_f32_16x16x32_bf16(a[ks].v, bl[1][ks].v, aU1, 0, 0, 0);
      aV1 = __builtin_amdgcn_mfma_f32_16x16x32_bf16(a[ks].v, br[1][ks].v, aV1, 0, 0, 0);
    }
#pragma unroll
    for(int r = 0; r < 4; ++r){
      size_t row = (size_t)(m0 + q * 4 + r);
      u[row * FDIM + 32 * g + r16]      = f2bf(aU0[r]);
      u[row * FDIM + 32 * g + 16 + r16] = f2bf(aU1[r]);
      v[row * FDIM + 32 * g + r16]      = f2bf(aV0[r] + bv0);
      v[row * FDIM + 32 * g + 16 + r16] = f2bf(aV1[r] + bv1);
    }
  }
}

// ---------- B-kernel (layers 1,2): h = relu(mean-gather(u) + v) ----------
// one wave per node; lanes = 16 chunks x 4 edge-slots
__global__ void k_aggv(const ushort* __restrict__ u, const ushort* __restrict__ v,
                       const int* __restrict__ rp, const int* __restrict__ col,
                       ushort* __restrict__ h){
  int node = (blockIdx.x * blockDim.x + threadIdx.x) >> 6;
  if(node >= NN) return;
  int l = threadIdx.x & 63;
  int c16 = l & 15, eg = l >> 4;
  int beg = rp[node], deg = rp[node + 1] - beg;
  float acc[8] = {0.f,0.f,0.f,0.f,0.f,0.f,0.f,0.f};
  const ushort* fbase = u + c16 * 8;

  for(int base = 0; base < deg; base += 64){
    int nchunk = min(deg - base, 64);
    int idx = col[beg + base + min(l, nchunk - 1)];
#pragma unroll 2
    for(int j = 0; j < nchunk; j += 4){
      int e = j + eg;
      int s = __shfl(idx, min(e, nchunk - 1));
      uint4 w = *(const uint4*)(fbase + (size_t)s * FDIM);
      if(e < nchunk){
        acc[0] += bflo(w.x); acc[1] += bfhi(w.x);
        acc[2] += bflo(w.y); acc[3] += bfhi(w.y);
        acc[4] += bflo(w.z); acc[5] += bfhi(w.z);
        acc[6] += bflo(w.w); acc[7] += bfhi(w.w);
      }
    }
  }
#pragma unroll
  for(int i = 0; i < 8; ++i){
    acc[i] += __shfl_xor(acc[i], 16);
    acc[i] += __shfl_xor(acc[i], 32);
  }
  if(eg == 0){
    float inv = 1.0f / (float)max(deg, 1);
    uint4 vv = *(const uint4*)(v + (size_t)node * FDIM + c16 * 8);
    float z0 = fmaxf(acc[0]*inv + bflo(vv.x), 0.f), z1 = fmaxf(acc[1]*inv + bfhi(vv.x), 0.f);
    float z2 = fmaxf(acc[2]*inv + bflo(vv.y), 0.f), z3 = fmaxf(acc[3]*inv + bfhi(vv.y), 0.f);
    float z4 = fmaxf(acc[4]*inv + bflo(vv.z), 0.f), z5 = fmaxf(acc[5]*inv + bfhi(vv.z), 0.f);
    float z6 = fmaxf(acc[6]*inv + bflo(vv.w), 0.f), z7 = fmaxf(acc[7]*inv + bfhi(vv.w), 0.f);
    uint4 o;
    o.x = (uint)f2bf(z0) | ((uint)f2bf(z1) << 16);
    o.y = (uint)f2bf(z2) | ((uint)f2bf(z3) << 16);
    o.z = (uint)f2bf(z4) | ((uint)f2bf(z5) << 16);
    o.w = (uint)f2bf(z6) | ((uint)f2bf(z7) << 16);
    *(uint4*)(h + (size_t)node * FDIM + c16 * 8) = o;
  }
}

// ---------- A3: u3 = h2@W3l^T, v3 = h2@W3r^T + b3 (both bf16, 40 cols) ----------
// block = 192 (3 waves); wave g owns cols [16g,16g+16) masked at 40; grid 625, 5 strips
__launch_bounds__(192)
__global__ void k_linuv40(const ushort* __restrict__ inB,
                          const float* __restrict__ Wl, const float* __restrict__ Wr,
                          const float* __restrict__ bias,
                          ushort* __restrict__ u3, ushort* __restrict__ v3){
  int g = threadIdx.x >> 6;
  int l = threadIdx.x & 63;
  int worker = blockIdx.x;
  int r16 = l & 15, q = l >> 4;
  int colw = 16 * g + r16;
  bool vcol = colw < FOUT;

  BF8 bl[4], br[4];
#pragma unroll
  for(int ks = 0; ks < 4; ++ks){
    BF8 t, w;
    if(vcol){
      const float* pl = Wl + colw * FDIM + q * 8 + 32 * ks;
      const float* pr = Wr + colw * FDIM + q * 8 + 32 * ks;
      float4 x0 = ((const float4*)pl)[0], x1 = ((const float4*)pl)[1];
      t.s[0]=f2bf(x0.x); t.s[1]=f2bf(x0.y); t.s[2]=f2bf(x0.z); t.s[3]=f2bf(x0.w);
      t.s[4]=f2bf(x1.x); t.s[5]=f2bf(x1.y); t.s[6]=f2bf(x1.z); t.s[7]=f2bf(x1.w);
      float4 y0 = ((const float4*)pr)[0], y1 = ((const float4*)pr)[1];
      w.s[0]=f2bf(y0.x); w.s[1]=f2bf(y0.y); w.s[2]=f2bf(y0.z); w.s[3]=f2bf(y0.w);
      w.s[4]=f2bf(y1.x); w.s[5]=f2bf(y1.y); w.s[6]=f2bf(y1.z); w.s[7]=f2bf(y1.w);
    } else {
      t.u = make_uint4(0,0,0,0);
      w.u = make_uint4(0,0,0,0);
    }
    bl[ks] = t; br[ks] = w;
  }
  float bv = vcol ? bias[colw] : 0.f;

  for(int s = 0; s < 5; ++s){
    int m0 = (worker * 5 + s) * 16;
    BF8 a[4];
    const ushort* pb = inB + (size_t)(m0 + r16) * FDIM + q * 8;
#pragma unroll
    for(int ks = 0; ks < 4; ++ks) a[ks].u = *(const uint4*)(pb + 32 * ks);
    f32x4 aU = {0,0,0,0}, aV = {0,0,0,0};
#pragma unroll
    for(int ks = 0; ks < 4; ++ks){
      aU = __builtin_amdgcn_mfma_f32_16x16x32_bf16(a[ks].v, bl[ks].v, aU, 0, 0, 0);
      aV = __builtin_amdgcn_mfma_f32_16x16x32_bf16(a[ks].v, br[ks].v, aV, 0, 0, 0);
    }
    if(vcol){
#pragma unroll
      for(int r = 0; r < 4; ++r){
        size_t row = (size_t)(m0 + q * 4 + r);
        u3[row * FOUT + colw] = f2bf(aU[r]);
        v3[row * FOUT + colw] = f2bf(aV[r] + bv);
      }
    }
  }
}

// ---------- B3: out = log_softmax(mean-gather(u3) + v3) ----------
// one wave per node; 20 chunks (2 bf16 dims each) x 3 edge-slots; lanes 60-63 idle
__global__ void k_agg40(const ushort* __restrict__ u3, const ushort* __restrict__ v3,
                        const int* __restrict__ rp, const int* __restrict__ col,
                        float* __restrict__ out){
  int node = (blockIdx.x * blockDim.x + threadIdx.x) >> 6;
  if(node >= NN) return;
  int l = threadIdx.x & 63;
  int c = l % 20, sl = l / 20;     // sl==3 -> idle for gather
  int beg = rp[node], deg = rp[node + 1] - beg;
  float a0 = 0.f, a1 = 0.f;
  const ushort* fbase = u3 + 2 * c;

  for(int base = 0; base < deg; base += 60){
    int nchunk = min(deg - base, 60);
    int idx = col[beg + base + min(l, nchunk - 1)];
#pragma unroll 2
    for(int j = 0; j < nchunk; j += 3){
      int e = j + sl;
      int s = __shfl(idx, min(e, nchunk - 1));
      uint w = *(const uint*)(fbase + (size_t)s * FOUT);
      if(sl < 3 && e < nchunk){
        a0 += bflo(w); a1 += bfhi(w);
      }
    }
  }
  // fold slots 1,2 into slot 0 (lanes 0..19)
  a0 += __shfl(a0, l + 20) + __shfl(a0, l + 40);
  a1 += __shfl(a1, l + 20) + __shfl(a1, l + 40);

  float inv = 1.0f / (float)max(deg, 1);
  float z0 = 0.f, z1 = 0.f;
  if(l < 20){
    uint vv = *(const uint*)(v3 + (size_t)node * FOUT + 2 * c);
    z0 = a0 * inv + bflo(vv);
    z1 = a1 * inv + bfhi(vv);
  }
  // wave-butterfly LSE over 40 values (2 per lane, lanes 0..19)
  float m = (l < 20) ? fmaxf(z0, z1) : -1e30f;
#pragma unroll
  for(int d = 1; d < 64; d <<= 1) m = fmaxf(m, __shfl_xor(m, d));
  float es = (l < 20) ? (__expf(z0 - m) + __expf(z1 - m)) : 0.f;
#pragma unroll
  for(int d = 1; d < 64; d <<= 1) es += __shfl_xor(es, d);
  float lse = m + __logf(es);
  if(l < 20){
    *(float2*)(out + (size_t)node * FOUT + 2 * c) = make_float2(z0 - lse, z1 - lse);
  }
}

extern "C" void kernel_launch(void* const* d_in, const int* in_sizes, int n_in,
                              void* d_out, int out_size, void* d_ws, size_t ws_size,
                              hipStream_t stream){
  const float* x   = (const float*)d_in[0];
  const void*  edges = d_in[1];
  const float* W1l = (const float*)d_in[2];
  const float* b1  = (const float*)d_in[3];
  const float* W1r = (const float*)d_in[4];
  const float* W2l = (const float*)d_in[5];
  const float* b2  = (const float*)d_in[6];
  const float* W2r = (const float*)d_in[7];
  const float* W3l = (const float*)d_in[8];
  const float* b3  = (const float*)d_in[9];
  const float* W3r = (const float*)d_in[10];
  float* out = (float*)d_out;

  char* ws = (char*)d_ws;
  size_t off = 0;
  auto alloc = [&](size_t bytes)->void*{
    void* p = ws + off;
    off += (bytes + 255) & ~(size_t)255;
    return p;
  };
  ushort* u    = (ushort*)alloc((size_t)NN * FDIM * 2);  // layer u / u3
  ushort* v    = (ushort*)alloc((size_t)NN * FDIM * 2);  // layer v / v3
  ushort* h    = (ushort*)alloc((size_t)NN * FDIM * 2);  // h1 then h2
  ushort* h2   = (ushort*)alloc((size_t)NN * FDIM * 2);
  int*    deg  = (int*)alloc((size_t)NN * 4);            // reused as cursor
  int*    rp   = (int*)alloc((size_t)(NN + 1) * 4);
  int*    col  = (int*)alloc((size_t)NE * 4);
  int*    bsum = (int*)alloc(1024);
  int*    flag = (int*)alloc(256);

  // CSR build
  k_zero_detect<<<(NN + 255) / 256, 256, 0, stream>>>((const unsigned long long*)edges, flag, deg);
  k_count<<<(NE + 255) / 256, 256, 0, stream>>>(edges, flag, deg);
  int nb = (NN + 255) / 256;  // 196
  k_scan1<<<nb, 256, 0, stream>>>(deg, rp, bsum);
  k_scan2<<<1, 256, 0, stream>>>(bsum, nb);
  k_scan3<<<nb, 256, 0, stream>>>(rp, bsum, deg);
  k_fill<<<(NE + 255) / 256, 256, 0, stream>>>(edges, flag, rp, deg, col);

  int aggGrid = (NN * 64 + 255) / 256;
  // layer 1 (f32 input)
  k_linuv<<<625, 256, 0, stream>>>(x, (const ushort*)nullptr, 1, W1l, W1r, b1, u, v);
  k_aggv<<<aggGrid, 256, 0, stream>>>(u, v, rp, col, h);
  // layer 2
  k_linuv<<<625, 256, 0, stream>>>((const float*)nullptr, h, 0, W2l, W2r, b2, u, v);
  k_aggv<<<aggGrid, 256, 0, stream>>>(u, v, rp, col, h2);
  // layer 3
  k_linuv40<<<625, 192, 0, stream>>>(h2, W3l, W3r, b3, u, v);
  k_agg40<<<aggGrid, 256, 0, stream>>>(u, v, rp, col, out);
}